// Round 1
// baseline (690.714 us; speedup 1.0000x reference)
//
#include <hip/hip_runtime.h>
#include <hip/hip_bf16.h>

// Problem constants (B=4, S=2048, H=2048, E=8, K=2)
#define T_TOK 8192
#define H_DIM 2048
#define NE 8

typedef float f32x4 __attribute__((ext_vector_type(4)));
typedef short s16x8 __attribute__((ext_vector_type(8)));

static __device__ __forceinline__ unsigned short f32_to_bf16(float f) {
    // round-to-nearest-even; inputs are finite (no NaN handling needed)
    unsigned int u = __builtin_bit_cast(unsigned int, f);
    unsigned int r = (u + 0x7FFFu + ((u >> 16) & 1u)) >> 16;
    return (unsigned short)r;
}

// ---------------------------------------------------------------------------
// Kernel 1: zero out-region + expert counts, convert X and W fp32 -> bf16.
// d_out / d_ws are re-poisoned 0xAA before every timed call, so this must run
// every launch.
// ---------------------------------------------------------------------------
__global__ __launch_bounds__(256) void prep_kernel(
        const float* __restrict__ x, const float* __restrict__ w,
        unsigned short* __restrict__ xb, unsigned short* __restrict__ wb,
        float* __restrict__ out, int* __restrict__ cnt) {
    const long g = (long)blockIdx.x * blockDim.x + threadIdx.x;
    const long nt = (long)gridDim.x * blockDim.x;
    if (g < NE) cnt[g] = 0;

    const long N_OUT4 = (long)T_TOK * H_DIM / 4;  // 4,194,304 float4
    float4* out4 = (float4*)out;
    for (long i = g; i < N_OUT4; i += nt) out4[i] = make_float4(0.f, 0.f, 0.f, 0.f);

    const float4* x4 = (const float4*)x;
    ushort4* xb4 = (ushort4*)xb;
    for (long i = g; i < N_OUT4; i += nt) {
        float4 v = x4[i];
        xb4[i] = make_ushort4(f32_to_bf16(v.x), f32_to_bf16(v.y),
                              f32_to_bf16(v.z), f32_to_bf16(v.w));
    }

    const long N_W4 = (long)NE * H_DIM * H_DIM / 4;  // 8,388,608 float4
    const float4* w4 = (const float4*)w;
    ushort4* wb4 = (ushort4*)wb;
    for (long i = g; i < N_W4; i += nt) {
        float4 v = w4[i];
        wb4[i] = make_ushort4(f32_to_bf16(v.x), f32_to_bf16(v.y),
                              f32_to_bf16(v.z), f32_to_bf16(v.w));
    }
}

// ---------------------------------------------------------------------------
// Kernel 2: router. fp32 logits (exact), softmax-free top-2 (monotone in
// logits), renormalized top-2 weights, atomic append into per-expert lists.
// One wave per 16 tokens; gate_w (64 KiB) staged in LDS once per block.
// ---------------------------------------------------------------------------
__global__ __launch_bounds__(256) void router_kernel(
        const float* __restrict__ x, const float* __restrict__ gate,
        float* __restrict__ logits, int* __restrict__ cnt,
        int* __restrict__ list, float* __restrict__ wl) {
    __shared__ float4 gs[NE * H_DIM / 4];  // 64 KiB
    const float4* g4 = (const float4*)gate;
    for (int i = threadIdx.x; i < NE * H_DIM / 4; i += 256) gs[i] = g4[i];
    __syncthreads();

    const int wave = threadIdx.x >> 6, lane = threadIdx.x & 63;
    const int wid = blockIdx.x * 4 + wave;  // 0..511 -> 16 tokens each

    for (int it = 0; it < 16; ++it) {
        const int t = wid * 16 + it;
        const float4* xr = (const float4*)(x + (long)t * H_DIM);
        float acc[NE];
#pragma unroll
        for (int e = 0; e < NE; ++e) acc[e] = 0.f;
#pragma unroll
        for (int i = 0; i < 8; ++i) {
            float4 xv = xr[i * 64 + lane];
#pragma unroll
            for (int e = 0; e < NE; ++e) {
                float4 gv = gs[e * 512 + i * 64 + lane];
                acc[e] += xv.x * gv.x + xv.y * gv.y + xv.z * gv.z + xv.w * gv.w;
            }
        }
#pragma unroll
        for (int e = 0; e < NE; ++e)
#pragma unroll
            for (int off = 32; off > 0; off >>= 1)
                acc[e] += __shfl_xor(acc[e], off, 64);

        if (lane == 0) {
            float l0 = -1e30f; int i0 = 0;
#pragma unroll
            for (int e = 0; e < NE; ++e)
                if (acc[e] > l0) { l0 = acc[e]; i0 = e; }
            float l1 = -1e30f; int i1 = 0;
#pragma unroll
            for (int e = 0; e < NE; ++e)
                if (e != i0 && acc[e] > l1) { l1 = acc[e]; i1 = e; }
            // normalized top-2 weights: softmax denom cancels
            float e1v = __expf(l1 - l0);
            float inv = 1.f / (1.f + e1v);
            float w0 = inv, w1 = e1v * inv;
#pragma unroll
            for (int e = 0; e < NE; ++e) logits[(long)t * NE + e] = acc[e];
            int p0 = atomicAdd(&cnt[i0], 1);
            list[i0 * T_TOK + p0] = t; wl[i0 * T_TOK + p0] = w0;
            int p1 = atomicAdd(&cnt[i1], 1);
            list[i1 * T_TOK + p1] = t; wl[i1 * T_TOK + p1] = w1;
        }
    }
}

// ---------------------------------------------------------------------------
// Kernel 3: grouped expert GEMM. Per expert e: Y = gather(X) @ W_e^T, scaled
// by per-token weight, atomicAdd into out. 128x128 tile, BK=64, 4 waves with
// 4x4 16x16x32 bf16 MFMA each. XOR-swizzled LDS: phys 16B-chunk =
// (row<<3) | (chunkcol ^ (row&7)) -> conflict-free b128 reads AND writes.
// ---------------------------------------------------------------------------
__global__ __launch_bounds__(256, 3) void moe_gemm(
        const unsigned short* __restrict__ xb, const unsigned short* __restrict__ wb,
        const int* __restrict__ cnt, const int* __restrict__ list,
        const float* __restrict__ wl, float* __restrict__ out) {
    __shared__ uint4 As[1024];  // 128 rows x 64 bf16 = 16 KiB
    __shared__ uint4 Bs[1024];
    __shared__ int tIdx[128];
    __shared__ float tw[128];

    const int bx = blockIdx.x;
    const int e  = bx >> 10;         // 1024 blocks per expert
    const int rt = (bx >> 4) & 63;   // 64 row tiles (max 8192 rows)
    const int ct = bx & 15;          // 16 col tiles
    const int n = cnt[e];
    const int row0 = rt << 7;
    if (row0 >= n) return;
    const int rv = min(128, n - row0);

    const int tid = threadIdx.x;
    if (tid < 128) {
        if (tid < rv) {
            tIdx[tid] = list[e * T_TOK + row0 + tid];
            tw[tid]   = wl[e * T_TOK + row0 + tid];
        } else { tIdx[tid] = 0; tw[tid] = 0.f; }
    }
    __syncthreads();

    const int wave = tid >> 6, lane = tid & 63;
    const int wm = (wave >> 1) << 6;   // 0 / 64
    const int wn = (wave & 1) << 6;    // 0 / 64
    const int quad = lane >> 4, l16 = lane & 15;

    f32x4 acc[4][4];
#pragma unroll
    for (int i = 0; i < 4; ++i)
#pragma unroll
        for (int j = 0; j < 4; ++j) acc[i][j] = (f32x4){0.f, 0.f, 0.f, 0.f};

    // Hoisted staging addresses: thread stages 16B chunks q = tid + i*256
    const unsigned short* aSrc[4];
    const unsigned short* bSrc[4];
    int dstc[4];
    const long wbase = (long)e * H_DIM * H_DIM + (long)(ct * 128) * H_DIM;
#pragma unroll
    for (int i = 0; i < 4; ++i) {
        int q = tid + i * 256;
        int r = q >> 3, c = q & 7;
        aSrc[i] = xb + (long)tIdx[r] * H_DIM + c * 8;
        bSrc[i] = wb + wbase + (long)r * H_DIM + c * 8;
        dstc[i] = (r << 3) | (c ^ (r & 7));
    }

    for (int kt = 0; kt < H_DIM / 64; ++kt) {
        const int k0 = kt * 64;
#pragma unroll
        for (int i = 0; i < 4; ++i) {
            As[dstc[i]] = *(const uint4*)(aSrc[i] + k0);
            Bs[dstc[i]] = *(const uint4*)(bSrc[i] + k0);
        }
        __syncthreads();
#pragma unroll
        for (int ks = 0; ks < 2; ++ks) {
            s16x8 af[4], bfr[4];
            const int kc = ks * 4 + quad;
#pragma unroll
            for (int i = 0; i < 4; ++i) {
                int r = wm + i * 16 + l16;
                af[i] = ((const s16x8*)As)[(r << 3) | (kc ^ (r & 7))];
            }
#pragma unroll
            for (int j = 0; j < 4; ++j) {
                int d = wn + j * 16 + l16;
                bfr[j] = ((const s16x8*)Bs)[(d << 3) | (kc ^ (d & 7))];
            }
#pragma unroll
            for (int i = 0; i < 4; ++i)
#pragma unroll
                for (int j = 0; j < 4; ++j)
                    acc[i][j] = __builtin_amdgcn_mfma_f32_16x16x32_bf16(
                        af[i], bfr[j], acc[i][j], 0, 0, 0);
        }
        __syncthreads();
    }

    // Epilogue: C/D layout col = lane&15, row = quad*4 + reg.
    const int colbase = ct * 128 + wn;
#pragma unroll
    for (int i = 0; i < 4; ++i) {
        const int rbase = wm + i * 16 + quad * 4;
#pragma unroll
        for (int jr = 0; jr < 4; ++jr) {
            const int r = rbase + jr;
            if (r < rv) {
                const float wgt = tw[r];
                const long orow = (long)tIdx[r] * H_DIM + colbase;
#pragma unroll
                for (int j = 0; j < 4; ++j)
                    atomicAdd(&out[orow + j * 16 + l16], acc[i][j][jr] * wgt);
            }
        }
    }
}

// ---------------------------------------------------------------------------
extern "C" void kernel_launch(void* const* d_in, const int* in_sizes, int n_in,
                              void* d_out, int out_size, void* d_ws, size_t ws_size,
                              hipStream_t stream) {
    (void)in_sizes; (void)n_in; (void)out_size; (void)ws_size;
    const float* x    = (const float*)d_in[0];   // [T, H] fp32
    const float* gate = (const float*)d_in[1];   // [E, H] fp32
    const float* w    = (const float*)d_in[2];   // [E, H, H] fp32

    float* out    = (float*)d_out;                       // [T, H]
    float* logits = out + (size_t)T_TOK * H_DIM;         // [T, E]

    char* ws = (char*)d_ws;
    unsigned short* xb = (unsigned short*)(ws);                 // 33,554,432 B
    unsigned short* wb = (unsigned short*)(ws + 33554432);      // 67,108,864 B
    int*   cnt  = (int*)(ws + 100663296);                       // 32 B
    int*   list = (int*)(ws + 100663328);                       // 262,144 B
    float* wl   = (float*)(ws + 100925472);                     // 262,144 B
    // total ws needed: ~101.2 MB

    prep_kernel<<<2048, 256, 0, stream>>>(x, w, xb, wb, out, cnt);
    router_kernel<<<128, 256, 0, stream>>>(x, gate, logits, cnt, list, wl);
    moe_gemm<<<8192, 256, 0, stream>>>(xb, wb, cnt, list, wl, out);
}

// Round 2
// 484.259 us; speedup vs baseline: 1.4263x; 1.4263x over previous
//
#include <hip/hip_runtime.h>
#include <hip/hip_bf16.h>

// Problem constants (B=4, S=2048, H=2048, E=8, K=2)
#define T_TOK 8192
#define H_DIM 2048
#define NE 8

typedef float f32x4 __attribute__((ext_vector_type(4)));
typedef short s16x8 __attribute__((ext_vector_type(8)));

typedef __attribute__((address_space(3))) unsigned int lds_uint;
typedef __attribute__((address_space(1))) const unsigned int glob_uint;

static __device__ __forceinline__ void async_ld16(const void* g, void* l) {
    // 64 lanes x 16B: global per-lane address -> LDS (wave-uniform base + lane*16)
    __builtin_amdgcn_global_load_lds((glob_uint*)g, (lds_uint*)l, 16, 0, 0);
}

static __device__ __forceinline__ unsigned short f32_to_bf16(float f) {
    unsigned int u = __builtin_bit_cast(unsigned int, f);
    unsigned int r = (u + 0x7FFFu + ((u >> 16) & 1u)) >> 16;
    return (unsigned short)r;
}

// ---------------------------------------------------------------------------
// Kernel 1: convert W fp32 -> bf16, zero expert counters.
// (out-zeroing moved to hipMemsetAsync; X conversion fused into router)
// ---------------------------------------------------------------------------
__global__ __launch_bounds__(256) void prep_kernel(
        const float* __restrict__ w, unsigned short* __restrict__ wb,
        int* __restrict__ cnt) {
    const long g = (long)blockIdx.x * 256 + threadIdx.x;
    if (g < NE) cnt[g] = 0;
    const long nt = (long)gridDim.x * 256;
    const long N_W4 = (long)NE * H_DIM * H_DIM / 4;  // 8,388,608 float4
    const float4* w4 = (const float4*)w;
    ushort4* wb4 = (ushort4*)wb;
    for (long i = g; i < N_W4; i += nt) {
        float4 v = w4[i];
        wb4[i] = make_ushort4(f32_to_bf16(v.x), f32_to_bf16(v.y),
                              f32_to_bf16(v.z), f32_to_bf16(v.w));
    }
}

// ---------------------------------------------------------------------------
// Kernel 2: router v2. 512 blocks x 16 tokens. Per wave: 4 tokens, fused
// fp32->bf16 X conversion. fp32 logits (exact), softmax-free top-2,
// per-block aggregated list append (8 atomics/block instead of 32).
// ---------------------------------------------------------------------------
__global__ __launch_bounds__(256) void router_kernel(
        const float* __restrict__ x, const float* __restrict__ gate,
        unsigned short* __restrict__ xb, float* __restrict__ logits,
        int* __restrict__ cnt, int* __restrict__ list, float* __restrict__ wl) {
    __shared__ float4 gs[NE * H_DIM / 4];  // 64 KiB
    __shared__ int aExp[32];
    __shared__ float aW[32];
    const float4* g4 = (const float4*)gate;
    for (int i = threadIdx.x; i < NE * H_DIM / 4; i += 256) gs[i] = g4[i];
    __syncthreads();

    const int wave = threadIdx.x >> 6, lane = threadIdx.x & 63;

    for (int it = 0; it < 4; ++it) {
        const int tok = wave * 4 + it;               // 0..15 within block
        const int t = blockIdx.x * 16 + tok;
        const float4* xr = (const float4*)(x + (long)t * H_DIM);
        ushort4* xw = (ushort4*)(xb + (long)t * H_DIM);
        float acc[NE];
#pragma unroll
        for (int e = 0; e < NE; ++e) acc[e] = 0.f;
#pragma unroll
        for (int i = 0; i < 8; ++i) {
            float4 xv = xr[i * 64 + lane];
            xw[i * 64 + lane] = make_ushort4(f32_to_bf16(xv.x), f32_to_bf16(xv.y),
                                             f32_to_bf16(xv.z), f32_to_bf16(xv.w));
#pragma unroll
            for (int e = 0; e < NE; ++e) {
                float4 gv = gs[e * 512 + i * 64 + lane];
                acc[e] += xv.x * gv.x + xv.y * gv.y + xv.z * gv.z + xv.w * gv.w;
            }
        }
#pragma unroll
        for (int e = 0; e < NE; ++e)
#pragma unroll
            for (int off = 32; off > 0; off >>= 1)
                acc[e] += __shfl_xor(acc[e], off, 64);

        if (lane == 0) {
            float l0 = -1e30f; int i0 = 0;
#pragma unroll
            for (int e = 0; e < NE; ++e)
                if (acc[e] > l0) { l0 = acc[e]; i0 = e; }
            float l1 = -1e30f; int i1 = 0;
#pragma unroll
            for (int e = 0; e < NE; ++e)
                if (e != i0 && acc[e] > l1) { l1 = acc[e]; i1 = e; }
            float e1v = __expf(l1 - l0);
            float inv = 1.f / (1.f + e1v);
#pragma unroll
            for (int e = 0; e < NE; ++e) logits[(long)t * NE + e] = acc[e];
            aExp[tok * 2] = i0;     aW[tok * 2] = inv;
            aExp[tok * 2 + 1] = i1; aW[tok * 2 + 1] = e1v * inv;
        }
    }
    __syncthreads();

    if (threadIdx.x < NE) {
        const int e = threadIdx.x;
        int c = 0;
#pragma unroll
        for (int k = 0; k < 32; ++k) c += (aExp[k] == e);
        if (c) {
            int pos = atomicAdd(&cnt[e], c);
            for (int k = 0; k < 32; ++k)
                if (aExp[k] == e) {
                    list[e * T_TOK + pos] = blockIdx.x * 16 + (k >> 1);
                    wl[e * T_TOK + pos] = aW[k];
                    ++pos;
                }
        }
    }
}

// ---------------------------------------------------------------------------
// Kernel 3: grouped expert GEMM, async staging. Per expert e: Y = gather(X)
// @ W_e^T, scaled by token weight, atomicAdd into out. 128x128 tile, BK=64,
// 4 waves of 4x4 16x16x32 bf16 MFMA. LDS layout XOR-swizzled: logical (row r,
// 16B-chunk c) lives at phys chunk (r<<3)|(c^(r&7)). global_load_lds writes
// phys-linear (wave base + lane*16), so each lane fetches the global column
// for its phys slot: c_log = (p&7)^(r&7) (involution). ds_read_b128 of a
// k-column then hits 2-way-max bank aliasing (free).
// ---------------------------------------------------------------------------
__global__ __launch_bounds__(256, 4) void moe_gemm(
        const unsigned short* __restrict__ xb, const unsigned short* __restrict__ wb,
        const int* __restrict__ cnt, const int* __restrict__ list,
        const float* __restrict__ wl, float* __restrict__ out) {
    __shared__ uint4 As[1024];  // 128 rows x 64 bf16 = 16 KiB
    __shared__ uint4 Bs[1024];
    __shared__ int tIdx[128];
    __shared__ float tw[128];

    const int bx = blockIdx.x;
    const int e  = bx >> 10;         // 1024 blocks per expert
    const int rt = (bx >> 4) & 63;   // 64 row tiles
    const int ct = bx & 15;          // 16 col tiles
    const int n = cnt[e];
    const int row0 = rt << 7;
    if (row0 >= n) return;
    const int rv = min(128, n - row0);

    const int tid = threadIdx.x;
    if (tid < 128) {
        if (tid < rv) {
            tIdx[tid] = list[e * T_TOK + row0 + tid];
            tw[tid]   = wl[e * T_TOK + row0 + tid];
        } else { tIdx[tid] = 0; tw[tid] = 0.f; }
    }
    __syncthreads();

    const int wave = tid >> 6, lane = tid & 63;
    const int wm = (wave >> 1) << 6;   // 0 / 64
    const int wn = (wave & 1) << 6;    // 0 / 64
    const int quad = lane >> 4, l16 = lane & 15;

    f32x4 acc[4][4];
#pragma unroll
    for (int i = 0; i < 4; ++i)
#pragma unroll
        for (int j = 0; j < 4; ++j) acc[i][j] = (f32x4){0.f, 0.f, 0.f, 0.f};

    // Per-lane global sources for async staging: phys chunk p = i*256+wave*64+lane
    const unsigned short* aSrc[4];
    const unsigned short* bSrc[4];
    const long wbase = (long)e * H_DIM * H_DIM + (long)(ct * 128) * H_DIM;
#pragma unroll
    for (int i = 0; i < 4; ++i) {
        const int p = i * 256 + wave * 64 + lane;
        const int r = p >> 3;
        const int c = (p & 7) ^ (r & 7);   // logical k-chunk for this phys slot
        aSrc[i] = xb + (long)tIdx[r] * H_DIM + c * 8;
        bSrc[i] = wb + wbase + (long)r * H_DIM + c * 8;
    }

    for (int kt = 0; kt < H_DIM / 64; ++kt) {
        const int k0 = kt * 64;
#pragma unroll
        for (int i = 0; i < 4; ++i) {
            async_ld16(aSrc[i] + k0, &As[i * 256 + wave * 64]);
            async_ld16(bSrc[i] + k0, &Bs[i * 256 + wave * 64]);
        }
        __syncthreads();
#pragma unroll
        for (int ks = 0; ks < 2; ++ks) {
            s16x8 af[4], bfr[4];
            const int kc = ks * 4 + quad;
#pragma unroll
            for (int i = 0; i < 4; ++i) {
                int r = wm + i * 16 + l16;
                af[i] = ((const s16x8*)As)[(r << 3) | (kc ^ (r & 7))];
            }
#pragma unroll
            for (int j = 0; j < 4; ++j) {
                int d = wn + j * 16 + l16;
                bfr[j] = ((const s16x8*)Bs)[(d << 3) | (kc ^ (d & 7))];
            }
#pragma unroll
            for (int i = 0; i < 4; ++i)
#pragma unroll
                for (int j = 0; j < 4; ++j)
                    acc[i][j] = __builtin_amdgcn_mfma_f32_16x16x32_bf16(
                        af[i], bfr[j], acc[i][j], 0, 0, 0);
        }
        __syncthreads();
    }

    // Epilogue: C/D layout col = lane&15, row = quad*4 + reg.
    const int colbase = ct * 128 + wn;
#pragma unroll
    for (int i = 0; i < 4; ++i) {
        const int rbase = wm + i * 16 + quad * 4;
#pragma unroll
        for (int jr = 0; jr < 4; ++jr) {
            const int r = rbase + jr;
            if (r < rv) {
                const float wgt = tw[r];
                const long orow = (long)tIdx[r] * H_DIM + colbase;
#pragma unroll
                for (int j = 0; j < 4; ++j)
                    atomicAdd(&out[orow + j * 16 + l16], acc[i][j][jr] * wgt);
            }
        }
    }
}

// ---------------------------------------------------------------------------
extern "C" void kernel_launch(void* const* d_in, const int* in_sizes, int n_in,
                              void* d_out, int out_size, void* d_ws, size_t ws_size,
                              hipStream_t stream) {
    (void)in_sizes; (void)n_in; (void)out_size; (void)ws_size;
    const float* x    = (const float*)d_in[0];   // [T, H] fp32
    const float* gate = (const float*)d_in[1];   // [E, H] fp32
    const float* w    = (const float*)d_in[2];   // [E, H, H] fp32

    float* out    = (float*)d_out;                       // [T, H]
    float* logits = out + (size_t)T_TOK * H_DIM;         // [T, E]

    char* ws = (char*)d_ws;
    unsigned short* xb = (unsigned short*)(ws);                 // 33,554,432 B
    unsigned short* wb = (unsigned short*)(ws + 33554432);      // 67,108,864 B
    int*   cnt  = (int*)(ws + 100663296);                       // 32 B
    int*   list = (int*)(ws + 100663328);                       // 262,144 B
    float* wl   = (float*)(ws + 100925472);                     // 262,144 B

    hipMemsetAsync(out, 0, (size_t)T_TOK * H_DIM * sizeof(float), stream);
    prep_kernel<<<2048, 256, 0, stream>>>(w, wb, cnt);
    router_kernel<<<512, 256, 0, stream>>>(x, gate, xb, logits, cnt, list, wl);
    moe_gemm<<<8192, 256, 0, stream>>>(xb, wb, cnt, list, wl, out);
}